// Round 5
// baseline (76.662 us; speedup 1.0000x reference)
//
#include <hip/hip_runtime.h>

#define NCLS 512
#define DIM 512
#define D4 128            // float4 per row
#define NHB 16            // hist partial blocks
#define EPS 1e-6f
#define MARGIN 1.0f

// ---------- Kernel 1: label histogram -> per-block partials (no atomics global) ----------
__global__ __launch_bounds__(256)
void k_hist(const int* __restrict__ lab, int* __restrict__ hist_part, int N)
{
    __shared__ int h[NCLS];
    const int t = threadIdx.x;
    const int b = blockIdx.x;
    h[t] = 0; h[t + 256] = 0;
    __syncthreads();

    const int4* lab4 = (const int4*)lab;
    const int nv = N >> 2;               // 16384
    const int per = nv / NHB;            // 1024 int4 per block
    const int j0 = b * per;
    for (int j = j0 + t; j < j0 + per; j += 256) {
        const int4 l = lab4[j];
        atomicAdd(&h[l.x], 1);
        atomicAdd(&h[l.y], 1);
        atomicAdd(&h[l.z], 1);
        atomicAdd(&h[l.w], 1);
    }
    __syncthreads();
    hist_part[b * NCLS + t]       = h[t];
    hist_part[b * NCLS + t + 256] = h[t + 256];
}

// ---------- Kernel 2: reduce partials, exclusive scan, init cur + d_out ----------
__global__ __launch_bounds__(512)
void k_scan(const int* __restrict__ hist_part, int* __restrict__ cnts,
            int* __restrict__ offsets, int* __restrict__ cur, float* __restrict__ d_out)
{
    __shared__ int h[NCLS];
    const int t = threadIdx.x;
    int myc = 0;
    #pragma unroll
    for (int b = 0; b < NHB; ++b) myc += hist_part[b * NCLS + t];
    cnts[t] = myc;
    h[t] = myc;
    __syncthreads();
    for (int o = 1; o < NCLS; o <<= 1) {
        const int add = (t >= o) ? h[t - o] : 0;
        __syncthreads();
        h[t] += add;
        __syncthreads();
    }
    offsets[t] = h[t] - myc;
    cur[t]     = h[t] - myc;
    if (t == 0) d_out[0] = 0.f;
}

// ---------- Kernel 3: scatter indices into class-sorted order ----------
__global__ __launch_bounds__(256)
void k_scatter(const int* __restrict__ lab, int* __restrict__ cur,
               int* __restrict__ sorted, int N)
{
    int i = blockIdx.x * blockDim.x + threadIdx.x;
    const int stride = gridDim.x * blockDim.x;
    for (; i < N; i += stride) {
        const int c = lab[i];
        const int p = atomicAdd(&cur[c], 1);
        sorted[p] = i;
    }
}

// ---------- Kernel 4: gather-sum, 2 blocks per class, max occupancy ----------
// Block b: class c = b>>1, part p = b&1 (half the class's rows).
// 512 threads: col4 = t&127, rq = t>>7 (4 rows in parallel).
__global__ __launch_bounds__(512)
void k_gather(const float4* __restrict__ x4, const int* __restrict__ sorted,
              const int* __restrict__ offsets, const int* __restrict__ cnts,
              float4* __restrict__ cls_part4)
{
    const int c    = blockIdx.x >> 1;
    const int p    = blockIdx.x & 1;
    const int t    = threadIdx.x;
    const int col4 = t & 127;
    const int rq   = t >> 7;     // 0..3
    const int off  = offsets[c];
    const int cnt  = cnts[c];
    const int half = (cnt + 1) >> 1;
    const int start = off + p * half;
    int m = cnt - p * half;
    if (m > half) m = half;
    if (m < 0)    m = 0;

    __shared__ int    s_idx[512];
    __shared__ float4 s_red[512];

    float4 acc = make_float4(0.f, 0.f, 0.f, 0.f);

    for (int done = 0; done < m; done += 512) {
        const int chunk = min(m - done, 512);
        if (t < chunk) s_idx[t] = sorted[start + done + t];
        __syncthreads();

        int base = 0;
        for (; base + 16 <= chunk; base += 16) {
            const int i0 = s_idx[base + rq];
            const int i1 = s_idx[base + 4 + rq];
            const int i2 = s_idx[base + 8 + rq];
            const int i3 = s_idx[base + 12 + rq];
            const float4 v0 = x4[(size_t)i0 * D4 + col4];
            const float4 v1 = x4[(size_t)i1 * D4 + col4];
            const float4 v2 = x4[(size_t)i2 * D4 + col4];
            const float4 v3 = x4[(size_t)i3 * D4 + col4];
            acc.x += (v0.x + v1.x) + (v2.x + v3.x);
            acc.y += (v0.y + v1.y) + (v2.y + v3.y);
            acc.z += (v0.z + v1.z) + (v2.z + v3.z);
            acc.w += (v0.w + v1.w) + (v2.w + v3.w);
        }
        for (; base + rq < chunk; base += 4) {
            const int i = s_idx[base + rq];
            const float4 v = x4[(size_t)i * D4 + col4];
            acc.x += v.x; acc.y += v.y; acc.z += v.z; acc.w += v.w;
        }
        __syncthreads();
    }

    s_red[t] = acc;
    __syncthreads();
    if (t < 128) {
        float4 s = s_red[t];
        const float4 a = s_red[t + 128];
        const float4 b = s_red[t + 256];
        const float4 d = s_red[t + 384];
        s.x += (a.x + b.x) + d.x;
        s.y += (a.y + b.y) + d.y;
        s.z += (a.z + b.z) + d.z;
        s.w += (a.w + b.w) + d.w;
        cls_part4[((size_t)p * NCLS + c) * D4 + t] = s;
    }
}

// ---------- Kernel 5: total[d] = sum over 2*NCLS part-rows ----------
// 16 blocks x 256 thr: 8 float4-cols per block, 32 row-groups of 32 rows.
__global__ __launch_bounds__(256)
void k_total(const float4* __restrict__ cls_part4, float4* __restrict__ total4)
{
    const int t    = threadIdx.x;
    const int col4 = blockIdx.x * 8 + (t & 7);
    const int g    = t >> 3;   // 0..31
    float4 s = make_float4(0.f, 0.f, 0.f, 0.f);
    for (int r = g; r < 2 * NCLS; r += 32) {
        const float4 v = cls_part4[(size_t)r * D4 + col4];
        s.x += v.x; s.y += v.y; s.z += v.z; s.w += v.w;
    }
    __shared__ float4 red[256];
    red[t] = s;
    __syncthreads();
    if (t < 8) {
        float4 a = red[t];
        #pragma unroll
        for (int k = 1; k < 32; ++k) {
            const float4 b = red[t + 8 * k];
            a.x += b.x; a.y += b.y; a.z += b.z; a.w += b.w;
        }
        total4[col4] = a;
    }
}

// ---------- Kernel 6: per-class hinge, accumulate loss ----------
__global__ __launch_bounds__(256)
void k_finalize(const float* __restrict__ cls_part, const int* __restrict__ cnts,
                const float* __restrict__ total, float* __restrict__ d_out, int N)
{
    const int c   = blockIdx.x;
    const int tid = threadIdx.x;
    const int cnt = cnts[c];

    const float2 s0 = ((const float2*)cls_part)[c * (DIM / 2) + tid];
    const float2 s1 = ((const float2*)cls_part)[(NCLS + c) * (DIM / 2) + tid];
    const float2 t  = ((const float2*)total)[tid];
    const float sx = s0.x + s1.x;
    const float sy = s0.y + s1.y;

    float ss = 0.f;
    if (cnt > 0) {
        const float inv_c  = 1.f / (float)cnt;
        const float inv_nc = 1.f / (float)(N - cnt);
        const float d0 = sx * inv_c - (t.x - sx) * inv_nc + EPS;
        const float d1 = sy * inv_c - (t.y - sy) * inv_nc + EPS;
        ss = d0 * d0 + d1 * d1;
    }

    #pragma unroll
    for (int o = 1; o < 64; o <<= 1) ss += __shfl_xor(ss, o, 64);

    __shared__ float s_red[4];
    if ((tid & 63) == 0) s_red[tid >> 6] = ss;
    __syncthreads();

    if (tid == 0) {
        const float tot = (s_red[0] + s_red[1]) + (s_red[2] + s_red[3]);
        const float d = sqrtf(tot);
        const float w = fmaxf(MARGIN - d, 0.f);
        if (cnt > 0) atomicAdd(d_out, (float)cnt * w * w / (float)N);
    }
}

extern "C" void kernel_launch(void* const* d_in, const int* in_sizes, int n_in,
                              void* d_out, int out_size, void* d_ws, size_t ws_size,
                              hipStream_t stream)
{
    const float* x   = (const float*)d_in[0];
    const int*   lab = (const int*)d_in[1];
    float*       out = (float*)d_out;

    const int N = in_sizes[1];  // 65536 samples

    float* cls_part  = (float*)d_ws;                        // 2*NCLS*DIM f32 = 2 MiB
    float* total     = cls_part + (size_t)2 * NCLS * DIM;   // DIM f32
    int*   cnts      = (int*)(total + DIM);                 // NCLS
    int*   offsets   = cnts + NCLS;                         // NCLS
    int*   cur       = offsets + NCLS;                      // NCLS
    int*   hist_part = cur + NCLS;                          // NHB*NCLS
    int*   sorted    = hist_part + NHB * NCLS;              // N

    k_hist    <<<NHB, 256, 0, stream>>>(lab, hist_part, N);
    k_scan    <<<1, 512, 0, stream>>>(hist_part, cnts, offsets, cur, out);
    k_scatter <<<128, 256, 0, stream>>>(lab, cur, sorted, N);
    k_gather  <<<2 * NCLS, 512, 0, stream>>>((const float4*)x, sorted, offsets, cnts,
                                             (float4*)cls_part);
    k_total   <<<16, 256, 0, stream>>>((const float4*)cls_part, (float4*)total);
    k_finalize<<<NCLS, 256, 0, stream>>>(cls_part, cnts, total, out, N);
}